// Round 2
// baseline (578.206 us; speedup 1.0000x reference)
//
#include <hip/hip_runtime.h>

// CompGraphConv, CSR-gather restructuring (round 2):
//   comp_edge[v] = (SO[v] - cntO[v]*x[v]) @ W_O^T + cntO[v]*b_O
//               +  (SI[v] - cntI[v]*x[v]) @ W_I^T + cntI[v]*b_I
// Round 1 computed SO/SI by 76.8M fp32 scatter-atomics (337 MB atomic
// write-through, 318 us). Round 2 builds a by-dst CSR on device each call
// (histogram -> order-free offsets via wave scan + 1 atomic/wave -> fill),
// then each node PULLS its src features (bf16 table, cache-resident) and
// does the 3 fused GEMVs in the same kernel. No acc arrays, no big memset.

#define DF 64

__device__ __forceinline__ float lane_bcast(float v, int k) {
    return __builtin_bit_cast(float, __builtin_amdgcn_readlane(__builtin_bit_cast(int, v), k));
}
__device__ __forceinline__ float bf2f(unsigned short u) {
    return __builtin_bit_cast(float, ((unsigned int)u) << 16);
}

__global__ __launch_bounds__(256) void to_bf16(const float* __restrict__ x,
                                               unsigned short* __restrict__ xh, int n) {
    int i = blockIdx.x * 256 + threadIdx.x;
    if (i < n) {
        unsigned int u = __builtin_bit_cast(unsigned int, x[i]);
        unsigned int r = (u + 0x7fff + ((u >> 16) & 1)) >> 16;  // RNE
        xh[i] = (unsigned short)r;
    }
}

__global__ __launch_bounds__(256) void histo(const int* __restrict__ dst,
                                             int* __restrict__ deg,
                                             int E, int half, int N) {
    int e = blockIdx.x * 256 + threadIdx.x;
    if (e >= E) return;
    int d = dst[e];
    atomicAdd(&deg[(e < half ? 0 : N) + d], 1);
}

// Disjoint-region offsets without a global sort order: wave-exclusive scan of
// deg + one atomicAdd per wave on a global cursor. Any disjoint partition of
// srcList is valid since each slot's region is only read back via off/deg.
__global__ __launch_bounds__(256) void make_off(const int* __restrict__ deg,
                                                int* __restrict__ off,
                                                int* __restrict__ counter, int M) {
    int i = blockIdx.x * 256 + threadIdx.x;
    int lane = threadIdx.x & 63;
    int v = (i < M) ? deg[i] : 0;
    int sum = v;
    #pragma unroll
    for (int o = 1; o < 64; o <<= 1) {
        int u = __shfl_up(sum, o);
        if (lane >= o) sum += u;
    }
    int excl = sum - v;
    int total = __shfl(sum, 63);
    int base = 0;
    if (lane == 63) base = atomicAdd(counter, total);
    base = __shfl(base, 63);
    if (i < M) off[i] = base + excl;
}

// Consumes off (turns start offsets into end offsets); node kernel recovers
// start = off[slot] - deg[slot].
__global__ __launch_bounds__(256) void fill_csr(const int* __restrict__ src,
                                                const int* __restrict__ dst,
                                                int* __restrict__ off,
                                                int* __restrict__ srcList,
                                                int E, int half, int N) {
    int e = blockIdx.x * 256 + threadIdx.x;
    if (e >= E) return;
    int d = dst[e];
    int slot = (e < half ? 0 : N) + d;
    int pos = atomicAdd(&off[slot], 1);
    srcList[pos] = src[e];
}

__global__ __launch_bounds__(256) void node_kernel(
        const float* __restrict__ x, const float* __restrict__ r,
        const unsigned short* __restrict__ xh,
        const int* __restrict__ deg, const int* __restrict__ off,
        const int* __restrict__ srcList,
        const float* __restrict__ W_O, const float* __restrict__ b_O,
        const float* __restrict__ W_I, const float* __restrict__ b_I,
        const float* __restrict__ W_S, const float* __restrict__ b_S,
        float* __restrict__ out, int N) {
    __shared__ float wts[64 * 65];
    __shared__ float wto[64 * 65];
    __shared__ float wti[64 * 65];
    for (int i = threadIdx.x; i < 4096; i += 256) {
        int j = i >> 6, k = i & 63;
        wts[k * 65 + j] = W_S[i];
        wto[k * 65 + j] = W_O[i];
        wti[k * 65 + j] = W_I[i];
    }
    __syncthreads();

    const int lane = threadIdx.x & 63;
    const int wave = threadIdx.x >> 6;
    const float bs = b_S[lane], bo = b_O[lane], bi = b_I[lane];
    const float rv = r[lane];

    for (int base = blockIdx.x * 16; base < N; base += gridDim.x * 16) {
        const int v0 = base + wave * 4;
        float xs[4], aO[4], aI[4], acc[4];
        bool valid[4];
        #pragma unroll
        for (int i = 0; i < 4; i++) {
            int v = v0 + i;
            valid[i] = (v < N);
            int vc = valid[i] ? v : (N - 1);
            float xv = x[(size_t)vc * DF + lane];
            int dO = deg[vc], dI = deg[N + vc];
            int eO_end = off[vc],     eO_start = eO_end - dO;
            int eI_end = off[N + vc], eI_start = eI_end - dI;
            float sO = 0.f, sO2 = 0.f;
            int e = eO_start;
            for (; e + 2 <= eO_end; e += 2) {
                int s0 = srcList[e], s1 = srcList[e + 1];
                sO  += bf2f(xh[(size_t)s0 * DF + lane]);
                sO2 += bf2f(xh[(size_t)s1 * DF + lane]);
            }
            if (e < eO_end) sO += bf2f(xh[(size_t)srcList[e] * DF + lane]);
            sO += sO2;
            float sI = 0.f, sI2 = 0.f;
            e = eI_start;
            for (; e + 2 <= eI_end; e += 2) {
                int s0 = srcList[e], s1 = srcList[e + 1];
                sI  += bf2f(xh[(size_t)s0 * DF + lane]);
                sI2 += bf2f(xh[(size_t)s1 * DF + lane]);
            }
            if (e < eI_end) sI += bf2f(xh[(size_t)srcList[e] * DF + lane]);
            sI += sI2;
            float cO = (float)dO, cI = (float)dI;
            xs[i] = xv - rv;
            aO[i] = sO - cO * xv;
            aI[i] = sI - cI * xv;
            acc[i] = bs + cO * bo + cI * bi;
        }
        #pragma unroll 16
        for (int k = 0; k < 64; k++) {
            float ws = wts[k * 65 + lane];
            float wo = wto[k * 65 + lane];
            float wi = wti[k * 65 + lane];
            #pragma unroll
            for (int i = 0; i < 4; i++) {
                acc[i] += lane_bcast(xs[i], k) * ws
                        + lane_bcast(aO[i], k) * wo
                        + lane_bcast(aI[i], k) * wi;
            }
        }
        #pragma unroll
        for (int i = 0; i < 4; i++) {
            if (valid[i]) out[(size_t)(v0 + i) * DF + lane] = acc[i];
        }
    }
}

__global__ void r_transform(const float* __restrict__ r,
                            const float* __restrict__ W_R,
                            const float* __restrict__ b_R,
                            float* __restrict__ out, int N) {
    int j = threadIdx.x;  // 64 threads
    float s = b_R[j];
    #pragma unroll 16
    for (int k = 0; k < 64; k++) s += r[k] * W_R[j * 64 + k];
    out[(size_t)N * DF + j] = s;
}

extern "C" void kernel_launch(void* const* d_in, const int* in_sizes, int n_in,
                              void* d_out, int out_size, void* d_ws, size_t ws_size,
                              hipStream_t stream) {
    const float* x   = (const float*)d_in[0];
    const float* r   = (const float*)d_in[1];
    const int*   src = (const int*)d_in[2];
    const int*   dst = (const int*)d_in[3];
    const float* W_O = (const float*)d_in[4];
    const float* b_O = (const float*)d_in[5];
    const float* W_I = (const float*)d_in[6];
    const float* b_I = (const float*)d_in[7];
    const float* W_S = (const float*)d_in[8];
    const float* b_S = (const float*)d_in[9];
    const float* W_R = (const float*)d_in[10];
    const float* b_R = (const float*)d_in[11];
    float* out = (float*)d_out;

    const int N = in_sizes[0] / DF;
    const int E = in_sizes[2];
    const int half = E / 2;

    // ws layout: deg[2N] | counter[1] | off[2N] | srcList[E] | xh[N*64] (u16)
    int* deg     = (int*)d_ws;
    int* counter = deg + 2 * (size_t)N;
    int* off     = counter + 1;
    int* srcList = off + 2 * (size_t)N;
    unsigned short* xh = (unsigned short*)(srcList + E);

    hipMemsetAsync(deg, 0, (2 * (size_t)N + 1) * sizeof(int), stream);

    int nXH = N * DF;
    to_bf16<<<(nXH + 255) / 256, 256, 0, stream>>>(x, xh, nXH);
    histo<<<(E + 255) / 256, 256, 0, stream>>>(dst, deg, E, half, N);
    make_off<<<(2 * N + 255) / 256, 256, 0, stream>>>(deg, off, counter, 2 * N);
    fill_csr<<<(E + 255) / 256, 256, 0, stream>>>(src, dst, off, srcList, E, half, N);
    node_kernel<<<2048, 256, 0, stream>>>(x, r, xh, deg, off, srcList,
                                          W_O, b_O, W_I, b_I, W_S, b_S, out, N);
    r_transform<<<1, 64, 0, stream>>>(r, W_R, b_R, out, N);
}

// Round 3
// 487.417 us; speedup vs baseline: 1.1863x; 1.1863x over previous
//
#include <hip/hip_runtime.h>

// CompGraphConv round 3: CSR build + TWO-PHASE node path.
// Round 2's fused node_kernel was latency-bound (0.5 TB/s, occ 20%): the
// serial per-node gather loop had ~2 outstanding loads/wave and 50 KB LDS
// capped residency. Round 3 splits:
//   gather_sum: 1 wave per (node,half), no LDS, max occupancy, 4-unrolled
//               independent gathers -> writes aO/aI = S - cnt*x_v  (f16)
//   gemv_kernel: streaming 3-way fused GEMV with weights in LDS.

#define DF 64
typedef _Float16 f16;

__device__ __forceinline__ float lane_bcast(float v, int k) {
    return __builtin_bit_cast(float, __builtin_amdgcn_readlane(__builtin_bit_cast(int, v), k));
}

__global__ __launch_bounds__(256) void to_f16(const float* __restrict__ x,
                                              f16* __restrict__ xh, int n) {
    int i = blockIdx.x * 256 + threadIdx.x;
    if (i < n) xh[i] = (f16)x[i];
}

__global__ __launch_bounds__(256) void histo(const int* __restrict__ dst,
                                             int* __restrict__ deg,
                                             int E, int half, int N) {
    int e = blockIdx.x * 256 + threadIdx.x;
    if (e >= E) return;
    int d = dst[e];
    atomicAdd(&deg[(e < half ? 0 : N) + d], 1);
}

// Disjoint-region offsets without a global order: wave-exclusive scan of deg
// + one atomicAdd per wave on a global cursor.
__global__ __launch_bounds__(256) void make_off(const int* __restrict__ deg,
                                                int* __restrict__ off,
                                                int* __restrict__ counter, int M) {
    int i = blockIdx.x * 256 + threadIdx.x;
    int lane = threadIdx.x & 63;
    int v = (i < M) ? deg[i] : 0;
    int sum = v;
    #pragma unroll
    for (int o = 1; o < 64; o <<= 1) {
        int u = __shfl_up(sum, o);
        if (lane >= o) sum += u;
    }
    int excl = sum - v;
    int total = __shfl(sum, 63);
    int base = 0;
    if (lane == 63) base = atomicAdd(counter, total);
    base = __shfl(base, 63);
    if (i < M) off[i] = base + excl;
}

// Consumes off (start -> end); consumers recover start = off[slot]-deg[slot].
__global__ __launch_bounds__(256) void fill_csr(const int* __restrict__ src,
                                                const int* __restrict__ dst,
                                                int* __restrict__ off,
                                                int* __restrict__ srcList,
                                                int E, int half, int N) {
    int e = blockIdx.x * 256 + threadIdx.x;
    if (e >= E) return;
    int d = dst[e];
    int slot = (e < half ? 0 : N) + d;
    int pos = atomicAdd(&off[slot], 1);
    srcList[pos] = src[e];
}

// One wave per (node, half). aO[v] = SO[v] - cntO[v]*x[v]  (f16), same for I.
__global__ __launch_bounds__(256) void gather_sum(
        const f16* __restrict__ xh,
        const int* __restrict__ deg, const int* __restrict__ off,
        const int* __restrict__ srcList,
        f16* __restrict__ aO, f16* __restrict__ aI, int N) {
    int wid = (blockIdx.x * 256 + threadIdx.x) >> 6;
    int lane = threadIdx.x & 63;
    if (wid >= 2 * N) return;
    int d = deg[wid];
    int end = off[wid];
    int start = end - d;
    int v = (wid < N) ? wid : wid - N;

    float s0 = 0.f, s1 = 0.f, s2 = 0.f, s3 = 0.f;
    int e = start;
    for (; e + 4 <= end; e += 4) {   // wave-uniform trip count, no divergence
        int i0 = srcList[e], i1 = srcList[e + 1];
        int i2 = srcList[e + 2], i3 = srcList[e + 3];
        s0 += (float)xh[(size_t)i0 * DF + lane];
        s1 += (float)xh[(size_t)i1 * DF + lane];
        s2 += (float)xh[(size_t)i2 * DF + lane];
        s3 += (float)xh[(size_t)i3 * DF + lane];
    }
    for (; e < end; e++) s0 += (float)xh[(size_t)srcList[e] * DF + lane];
    float sum = (s0 + s1) + (s2 + s3);
    float xv = (float)xh[(size_t)v * DF + lane];
    float a = sum - (float)d * xv;
    f16* dstp = (wid < N) ? aO : aI;
    dstp[(size_t)v * DF + lane] = (f16)a;
}

__global__ __launch_bounds__(256) void gemv_kernel(
        const float* __restrict__ x, const float* __restrict__ r,
        const f16* __restrict__ aO, const f16* __restrict__ aI,
        const int* __restrict__ deg,
        const float* __restrict__ W_O, const float* __restrict__ b_O,
        const float* __restrict__ W_I, const float* __restrict__ b_I,
        const float* __restrict__ W_S, const float* __restrict__ b_S,
        float* __restrict__ out, int N) {
    __shared__ float wts[64 * 65];
    __shared__ float wto[64 * 65];
    __shared__ float wti[64 * 65];
    for (int i = threadIdx.x; i < 4096; i += 256) {
        int j = i >> 6, k = i & 63;
        wts[k * 65 + j] = W_S[i];
        wto[k * 65 + j] = W_O[i];
        wti[k * 65 + j] = W_I[i];
    }
    __syncthreads();

    const int lane = threadIdx.x & 63;
    const int wave = threadIdx.x >> 6;
    const float bs = b_S[lane], bo = b_O[lane], bi = b_I[lane];
    const float rv = r[lane];

    for (int base = blockIdx.x * 16; base < N; base += gridDim.x * 16) {
        const int v0 = base + wave * 4;
        float xs[4], vO[4], vI[4], acc[4];
        bool valid[4];
        #pragma unroll
        for (int i = 0; i < 4; i++) {
            int v = v0 + i;
            valid[i] = (v < N);
            int vc = valid[i] ? v : (N - 1);
            float xv = x[(size_t)vc * DF + lane];
            float cO = (float)deg[vc], cI = (float)deg[N + vc];
            xs[i] = xv - rv;
            vO[i] = (float)aO[(size_t)vc * DF + lane];
            vI[i] = (float)aI[(size_t)vc * DF + lane];
            acc[i] = bs + cO * bo + cI * bi;
        }
        #pragma unroll 16
        for (int k = 0; k < 64; k++) {
            float ws = wts[k * 65 + lane];
            float wo = wto[k * 65 + lane];
            float wi = wti[k * 65 + lane];
            #pragma unroll
            for (int i = 0; i < 4; i++) {
                acc[i] += lane_bcast(xs[i], k) * ws
                        + lane_bcast(vO[i], k) * wo
                        + lane_bcast(vI[i], k) * wi;
            }
        }
        #pragma unroll
        for (int i = 0; i < 4; i++) {
            if (valid[i]) out[(size_t)(v0 + i) * DF + lane] = acc[i];
        }
    }
}

__global__ void r_transform(const float* __restrict__ r,
                            const float* __restrict__ W_R,
                            const float* __restrict__ b_R,
                            float* __restrict__ out, int N) {
    int j = threadIdx.x;  // 64 threads
    float s = b_R[j];
    #pragma unroll 16
    for (int k = 0; k < 64; k++) s += r[k] * W_R[j * 64 + k];
    out[(size_t)N * DF + j] = s;
}

extern "C" void kernel_launch(void* const* d_in, const int* in_sizes, int n_in,
                              void* d_out, int out_size, void* d_ws, size_t ws_size,
                              hipStream_t stream) {
    const float* x   = (const float*)d_in[0];
    const float* r   = (const float*)d_in[1];
    const int*   src = (const int*)d_in[2];
    const int*   dst = (const int*)d_in[3];
    const float* W_O = (const float*)d_in[4];
    const float* b_O = (const float*)d_in[5];
    const float* W_I = (const float*)d_in[6];
    const float* b_I = (const float*)d_in[7];
    const float* W_S = (const float*)d_in[8];
    const float* b_S = (const float*)d_in[9];
    const float* W_R = (const float*)d_in[10];
    const float* b_R = (const float*)d_in[11];
    float* out = (float*)d_out;

    const int N = in_sizes[0] / DF;
    const int E = in_sizes[2];
    const int half = E / 2;

    // ws: deg[2N] | counter[1] | off[2N] | srcList[E] | xh[N*64] f16
    //     | aO[N*64] f16 | aI[N*64] f16   (~44 MB)
    int* deg     = (int*)d_ws;
    int* counter = deg + 2 * (size_t)N;
    int* off     = counter + 1;
    int* srcList = off + 2 * (size_t)N;
    f16* xh = (f16*)(srcList + E);
    f16* aO = xh + (size_t)N * DF;
    f16* aI = aO + (size_t)N * DF;

    hipMemsetAsync(deg, 0, (2 * (size_t)N + 1) * sizeof(int), stream);

    int nXH = N * DF;
    to_f16<<<(nXH + 255) / 256, 256, 0, stream>>>(x, xh, nXH);
    histo<<<(E + 255) / 256, 256, 0, stream>>>(dst, deg, E, half, N);
    make_off<<<(2 * N + 255) / 256, 256, 0, stream>>>(deg, off, counter, 2 * N);
    fill_csr<<<(E + 255) / 256, 256, 0, stream>>>(src, dst, off, srcList, E, half, N);

    int nWaves = 2 * N;                        // one wave per (node, half)
    int gsBlocks = (nWaves + 3) / 4;           // 4 waves per block
    gather_sum<<<gsBlocks, 256, 0, stream>>>(xh, deg, off, srcList, aO, aI, N);

    gemv_kernel<<<2048, 256, 0, stream>>>(x, r, aO, aI, deg,
                                          W_O, b_O, W_I, b_I, W_S, b_S, out, N);
    r_transform<<<1, 64, 0, stream>>>(r, W_R, b_R, out, N);
}

// Round 4
// 407.818 us; speedup vs baseline: 1.4178x; 1.1952x over previous
//
#include <hip/hip_runtime.h>

// CompGraphConv round 4: MFMA epilogue GEMM.
// Round 3's gemv_kernel was VALU-bound (83% VALUBusy, 133 us): per k-step it
// spent half its issue slots on v_readlane broadcasts. The node transform is
// really C[N,64] = [x-r | aO | aI] @ [W_S;W_O;W_I]^T -- a skinny GEMM.
// Round 4 computes it with mfma_f32_16x16x32_f16 (A,B tiles in LDS, rows
// padded to 200 f16 = 4-bank stride => only free 2-way conflicts), bias
// bs + cO*bo + cI*bi folded into the epilogue. CSR build + gather unchanged.

#define DF 64
#define AROW 200  // padded LDS row length (f16) for A/B tiles
typedef _Float16 f16;
typedef f16 f16x8 __attribute__((ext_vector_type(8)));
typedef float f32x4 __attribute__((ext_vector_type(4)));

// ---- fused: x -> f16 table, plus dst-degree histogram
__global__ __launch_bounds__(256) void prep(const float* __restrict__ x,
                                            f16* __restrict__ xh, int n,
                                            const int* __restrict__ dst,
                                            int* __restrict__ deg,
                                            int E, int half, int N) {
    int i = blockIdx.x * 256 + threadIdx.x;
    if (i < n) xh[i] = (f16)x[i];
    if (i < E) {
        int d = dst[i];
        atomicAdd(&deg[(i < half ? 0 : N) + d], 1);
    }
}

// Disjoint-region offsets without a global order: wave-exclusive scan of deg
// + one atomicAdd per wave on a global cursor.
__global__ __launch_bounds__(256) void make_off(const int* __restrict__ deg,
                                                int* __restrict__ off,
                                                int* __restrict__ counter, int M) {
    int i = blockIdx.x * 256 + threadIdx.x;
    int lane = threadIdx.x & 63;
    int v = (i < M) ? deg[i] : 0;
    int sum = v;
    #pragma unroll
    for (int o = 1; o < 64; o <<= 1) {
        int u = __shfl_up(sum, o);
        if (lane >= o) sum += u;
    }
    int excl = sum - v;
    int total = __shfl(sum, 63);
    int base = 0;
    if (lane == 63) base = atomicAdd(counter, total);
    base = __shfl(base, 63);
    if (i < M) off[i] = base + excl;
}

// Consumes off (start -> end); consumers recover start = off[slot]-deg[slot].
__global__ __launch_bounds__(256) void fill_csr(const int* __restrict__ src,
                                                const int* __restrict__ dst,
                                                int* __restrict__ off,
                                                int* __restrict__ srcList,
                                                int E, int half, int N) {
    int e = blockIdx.x * 256 + threadIdx.x;
    if (e >= E) return;
    int d = dst[e];
    int slot = (e < half ? 0 : N) + d;
    int pos = atomicAdd(&off[slot], 1);
    srcList[pos] = src[e];
}

// One wave per (node, half). aO[v] = SO[v] - cntO[v]*x[v]  (f16), same for I.
__global__ __launch_bounds__(256) void gather_sum(
        const f16* __restrict__ xh,
        const int* __restrict__ deg, const int* __restrict__ off,
        const int* __restrict__ srcList,
        f16* __restrict__ aO, f16* __restrict__ aI, int N) {
    int wid = (blockIdx.x * 256 + threadIdx.x) >> 6;
    int lane = threadIdx.x & 63;
    if (wid >= 2 * N) return;
    int d = deg[wid];
    int end = off[wid];
    int start = end - d;
    int v = (wid < N) ? wid : wid - N;

    float s0 = 0.f, s1 = 0.f, s2 = 0.f, s3 = 0.f;
    int e = start;
    for (; e + 4 <= end; e += 4) {   // wave-uniform trip count, no divergence
        int i0 = srcList[e], i1 = srcList[e + 1];
        int i2 = srcList[e + 2], i3 = srcList[e + 3];
        s0 += (float)xh[(size_t)i0 * DF + lane];
        s1 += (float)xh[(size_t)i1 * DF + lane];
        s2 += (float)xh[(size_t)i2 * DF + lane];
        s3 += (float)xh[(size_t)i3 * DF + lane];
    }
    for (; e < end; e++) s0 += (float)xh[(size_t)srcList[e] * DF + lane];
    float sum = (s0 + s1) + (s2 + s3);
    float xv = (float)xh[(size_t)v * DF + lane];
    float a = sum - (float)d * xv;
    f16* dstp = (wid < N) ? aO : aI;
    dstp[(size_t)v * DF + lane] = (f16)a;
}

// C[N,64] = [x-r | aO | aI] @ [W_S;W_O;W_I]^T via mfma_f32_16x16x32_f16.
// Per block: 64-node A tile + full B^T in LDS; wave w owns nodes w*16..+15
// and all 4 output column tiles (16 accumulator VGPRs).
__global__ __launch_bounds__(256) void gemv_mfma(
        const float* __restrict__ x, const float* __restrict__ r,
        const f16* __restrict__ aO, const f16* __restrict__ aI,
        const int* __restrict__ deg,
        const float* __restrict__ W_O, const float* __restrict__ b_O,
        const float* __restrict__ W_I, const float* __restrict__ b_I,
        const float* __restrict__ W_S, const float* __restrict__ b_S,
        float* __restrict__ out, int N, int nTiles) {
    __shared__ f16 Al[64 * AROW];
    __shared__ f16 Bl[64 * AROW];

    // stage B^T rows: Bl[j][:] = [W_S[j][0:64] | W_O[j][0:64] | W_I[j][0:64]]
    for (int idx = threadIdx.x; idx < 4096; idx += 256) {
        int j = idx >> 6, k = idx & 63;
        Bl[j * AROW + k]       = (f16)W_S[idx];
        Bl[j * AROW + 64 + k]  = (f16)W_O[idx];
        Bl[j * AROW + 128 + k] = (f16)W_I[idx];
    }

    const int lane = threadIdx.x & 63;
    const int wave = threadIdx.x >> 6;
    const int mlane = lane & 15;       // A-row within tile / B^T row (= col j)
    const int koff = (lane >> 4) * 8;  // k offset within a K=32 step

    for (int tile = blockIdx.x; tile < nTiles; tile += gridDim.x) {
        const int vbase = tile * 64;
        __syncthreads();   // Bl visible (iter 0); Al free of prior readers
        for (int idx = threadIdx.x; idx < 4096; idx += 256) {
            int nd = idx >> 6, k = idx & 63;
            int v = vbase + nd;
            bool ok = (v < N);
            size_t g = (size_t)(ok ? v : 0) * DF + k;
            Al[nd * AROW + k]       = ok ? (f16)(x[g] - r[k]) : (f16)0.f;
            Al[nd * AROW + 64 + k]  = ok ? aO[g] : (f16)0.f;
            Al[nd * AROW + 128 + k] = ok ? aI[g] : (f16)0.f;
        }
        __syncthreads();

        f32x4 acc0 = {0,0,0,0}, acc1 = {0,0,0,0}, acc2 = {0,0,0,0}, acc3 = {0,0,0,0};
        const f16* arow  = &Al[(wave * 16 + mlane) * AROW + koff];
        const f16* brow0 = &Bl[mlane * AROW + koff];
        #pragma unroll
        for (int s = 0; s < 6; s++) {
            f16x8 af = *(const f16x8*)(arow + s * 32);
            f16x8 b0 = *(const f16x8*)(brow0 + s * 32);
            f16x8 b1 = *(const f16x8*)(brow0 + 16 * AROW + s * 32);
            f16x8 b2 = *(const f16x8*)(brow0 + 32 * AROW + s * 32);
            f16x8 b3 = *(const f16x8*)(brow0 + 48 * AROW + s * 32);
            acc0 = __builtin_amdgcn_mfma_f32_16x16x32_f16(af, b0, acc0, 0, 0, 0);
            acc1 = __builtin_amdgcn_mfma_f32_16x16x32_f16(af, b1, acc1, 0, 0, 0);
            acc2 = __builtin_amdgcn_mfma_f32_16x16x32_f16(af, b2, acc2, 0, 0, 0);
            acc3 = __builtin_amdgcn_mfma_f32_16x16x32_f16(af, b3, acc3, 0, 0, 0);
        }

        // C/D layout: col = lane&15, row = (lane>>4)*4 + reg
        const int mrow0 = (lane >> 4) * 4;
        #pragma unroll
        for (int reg = 0; reg < 4; reg++) {
            int v = vbase + wave * 16 + mrow0 + reg;
            if (v >= N) continue;
            float cO = (float)deg[v], cI = (float)deg[N + v];
            float a0 = acc0[reg], a1 = acc1[reg], a2 = acc2[reg], a3 = acc3[reg];
            int j0 = mlane;
            out[(size_t)v * DF + j0]      = a0 + b_S[j0]      + cO * b_O[j0]      + cI * b_I[j0];
            out[(size_t)v * DF + 16 + j0] = a1 + b_S[16 + j0] + cO * b_O[16 + j0] + cI * b_I[16 + j0];
            out[(size_t)v * DF + 32 + j0] = a2 + b_S[32 + j0] + cO * b_O[32 + j0] + cI * b_I[32 + j0];
            out[(size_t)v * DF + 48 + j0] = a3 + b_S[48 + j0] + cO * b_O[48 + j0] + cI * b_I[48 + j0];
        }
    }
}

__global__ void r_transform(const float* __restrict__ r,
                            const float* __restrict__ W_R,
                            const float* __restrict__ b_R,
                            float* __restrict__ out, int N) {
    int j = threadIdx.x;  // 64 threads
    float s = b_R[j];
    #pragma unroll 16
    for (int k = 0; k < 64; k++) s += r[k] * W_R[j * 64 + k];
    out[(size_t)N * DF + j] = s;
}

extern "C" void kernel_launch(void* const* d_in, const int* in_sizes, int n_in,
                              void* d_out, int out_size, void* d_ws, size_t ws_size,
                              hipStream_t stream) {
    const float* x   = (const float*)d_in[0];
    const float* r   = (const float*)d_in[1];
    const int*   src = (const int*)d_in[2];
    const int*   dst = (const int*)d_in[3];
    const float* W_O = (const float*)d_in[4];
    const float* b_O = (const float*)d_in[5];
    const float* W_I = (const float*)d_in[6];
    const float* b_I = (const float*)d_in[7];
    const float* W_S = (const float*)d_in[8];
    const float* b_S = (const float*)d_in[9];
    const float* W_R = (const float*)d_in[10];
    const float* b_R = (const float*)d_in[11];
    float* out = (float*)d_out;

    const int N = in_sizes[0] / DF;
    const int E = in_sizes[2];
    const int half = E / 2;

    // ws: deg[2N] | counter[1] | off[2N] | srcList[E] | xh[N*64] f16
    //     | aO[N*64] f16 | aI[N*64] f16
    int* deg     = (int*)d_ws;
    int* counter = deg + 2 * (size_t)N;
    int* off     = counter + 1;
    int* srcList = off + 2 * (size_t)N;
    f16* xh = (f16*)(srcList + E);
    f16* aO = xh + (size_t)N * DF;
    f16* aI = aO + (size_t)N * DF;

    hipMemsetAsync(deg, 0, (2 * (size_t)N + 1) * sizeof(int), stream);

    int nXH = N * DF;
    int prepGrid = ((nXH > E ? nXH : E) + 255) / 256;
    prep<<<prepGrid, 256, 0, stream>>>(x, xh, nXH, dst, deg, E, half, N);
    make_off<<<(2 * N + 255) / 256, 256, 0, stream>>>(deg, off, counter, 2 * N);
    fill_csr<<<(E + 255) / 256, 256, 0, stream>>>(src, dst, off, srcList, E, half, N);

    int nWaves = 2 * N;                        // one wave per (node, half)
    int gsBlocks = (nWaves + 3) / 4;           // 4 waves per block
    gather_sum<<<gsBlocks, 256, 0, stream>>>(xh, deg, off, srcList, aO, aI, N);

    int nTiles = (N + 63) / 64;
    gemv_mfma<<<768, 256, 0, stream>>>(x, r, aO, aI, deg,
                                       W_O, b_O, W_I, b_I, W_S, b_S,
                                       out, N, nTiles);
    r_transform<<<1, 64, 0, stream>>>(r, W_R, b_R, out, N);
}

// Round 5
// 299.313 us; speedup vs baseline: 1.9318x; 1.3625x over previous
//
#include <hip/hip_runtime.h>

// CompGraphConv round 5: bucketed counting sort + in-place A-matrix.
//
// Identity: with y = x - r,  SO[v] - cO*x[v] = sum_e y[src] - cO*y[v]
// (the r terms cancel), so the whole pipeline runs on y.
// A[v] = [ y[v] | aO[v] | aI[v] ]  (192 f16 = 384 B row, 16B-aligned,
// the three segments live on disjoint cache lines).
//
// CSR build (round-4 fill_csr: 87 us, 74.7 MB writes for a 4.8 MB payload =
// full 64B-line amplification on random 4B scatter; plus ~40 us of histo
// atomics hidden in prep) is replaced by a bucketed counting sort:
//   A: bucket counts via LDS histograms (256 keys/bucket)
//   B: one-block scan -> bucket bases + cursors
//   C: append packed (src | lk<<24) 4B pairs per bucket (temporally
//      clustered per line -> mergeable, unlike random scatter)
//   D: per-bucket LDS counting sort -> DENSE deg/off/srcList writes
// gemv: MFMA with A-frags straight from global (no LDS, no barriers),
// f16 weights broadcast through L1.

#define DF 64
#define BSH 8               // 256 keys per bucket
#define CAP 4096            // max edges/bucket (avg ~1536, Poisson)
#define CPAD 16             // ints of padding per bucket counter (64B line)
typedef _Float16 f16;
typedef f16 f16x8 __attribute__((ext_vector_type(8)));
typedef f16 f16x2 __attribute__((ext_vector_type(2)));
typedef float f32x4 __attribute__((ext_vector_type(4)));

// y = x - r into A rows; W_{S,O,I} -> f16 table Wf.
__global__ __launch_bounds__(256) void prep(const float* __restrict__ x,
                                            const float* __restrict__ r,
                                            f16* __restrict__ A,
                                            const float* __restrict__ W_S,
                                            const float* __restrict__ W_O,
                                            const float* __restrict__ W_I,
                                            f16* __restrict__ Wf, int N) {
    int t = blockIdx.x * 256 + threadIdx.x;
    int ny = N * 32;                      // f16x2 pairs of y
    if (t < ny) {
        int v = t >> 5, k = (t & 31) * 2;
        float y0 = x[(size_t)v * DF + k]     - r[k];
        float y1 = x[(size_t)v * DF + k + 1] - r[k + 1];
        f16x2 p = {(f16)y0, (f16)y1};
        *(f16x2*)(A + (size_t)v * 192 + k) = p;
    }
    if (t < 6144) {                       // 3*4096 weight elems as pairs
        int w = t / 2048;
        int i = (t % 2048) * 2;
        const float* W = (w == 0) ? W_S : (w == 1) ? W_O : W_I;
        f16x2 p = {(f16)W[i], (f16)W[i + 1]};
        *(f16x2*)(Wf + w * 4096 + i) = p;
    }
}

__global__ __launch_bounds__(256) void bucket_count(const int* __restrict__ dst,
                                                    int* __restrict__ bucketCnt,
                                                    int E, int half, int N, int NB) {
    __shared__ int lc[1024];
    for (int i = threadIdx.x; i < NB; i += 256) lc[i] = 0;
    __syncthreads();
    int stride = gridDim.x * 256;
    for (int e = blockIdx.x * 256 + threadIdx.x; e < E; e += stride) {
        int key = dst[e] + (e < half ? 0 : N);
        atomicAdd(&lc[key >> BSH], 1);
    }
    __syncthreads();
    for (int i = threadIdx.x; i < NB; i += 256) {
        int c = lc[i];
        if (c) atomicAdd(&bucketCnt[i * CPAD], c);
    }
}

__global__ __launch_bounds__(1024) void bucket_scan(const int* __restrict__ bucketCnt,
                                                    int* __restrict__ bucketBase,
                                                    int* __restrict__ cur, int NB) {
    __shared__ int s[1024];
    int t = threadIdx.x;
    int v = (t < NB) ? bucketCnt[t * CPAD] : 0;
    s[t] = v;
    __syncthreads();
    #pragma unroll
    for (int o = 1; o < 1024; o <<= 1) {
        int u = (t >= o) ? s[t - o] : 0;
        __syncthreads();
        s[t] += u;
        __syncthreads();
    }
    if (t < NB) {
        int base = s[t] - v;    // exclusive
        bucketBase[t] = base;
        cur[t * CPAD] = base;
    }
}

__global__ __launch_bounds__(256) void scatter_pairs(const int* __restrict__ src,
                                                     const int* __restrict__ dst,
                                                     int* __restrict__ cur,
                                                     unsigned int* __restrict__ pairBuf,
                                                     int E, int half, int N) {
    int e = blockIdx.x * 256 + threadIdx.x;
    if (e >= E) return;
    int key = dst[e] + (e < half ? 0 : N);
    int b = key >> BSH;
    int pos = atomicAdd(&cur[b * CPAD], 1);
    pairBuf[pos] = (unsigned int)src[e] | ((unsigned int)(key & 255) << 24);
}

__global__ __launch_bounds__(256) void bucket_sort(const unsigned int* __restrict__ pairBuf,
                                                   const int* __restrict__ bucketBase,
                                                   const int* __restrict__ bucketCnt,
                                                   int* __restrict__ deg,
                                                   int* __restrict__ off,
                                                   int* __restrict__ srcList, int M) {
    __shared__ unsigned int P[CAP];
    __shared__ int cnt[256];
    __shared__ int pos[256];
    int b = blockIdx.x;
    int base = bucketBase[b];
    int n = bucketCnt[b * CPAD];
    if (n > CAP) n = CAP;     // statistically unreachable; guards LDS OOB
    int t = threadIdx.x;
    cnt[t] = 0;
    __syncthreads();
    for (int i = t; i < n; i += 256) {
        unsigned int p = pairBuf[base + i];
        P[i] = p;
        atomicAdd(&cnt[p >> 24], 1);
    }
    __syncthreads();
    int v = cnt[t];
    pos[t] = v;
    __syncthreads();
    #pragma unroll
    for (int o = 1; o < 256; o <<= 1) {
        int u = (t >= o) ? pos[t - o] : 0;
        __syncthreads();
        pos[t] += u;
        __syncthreads();
    }
    int incl = pos[t];
    int key = (b << BSH) + t;
    if (key < M) {
        deg[key] = v;
        off[key] = base + incl;          // end offset; start = end - deg
    }
    __syncthreads();
    pos[t] = incl - v;                   // per-key write cursor (exclusive)
    __syncthreads();
    for (int i = t; i < n; i += 256) {
        unsigned int p = P[i];
        int lk = p >> 24;
        int loc = atomicAdd(&pos[lk], 1);
        srcList[base + loc] = (int)(p & 0xFFFFFFu);   // dense window in L2
    }
}

// One wave per (node, half): A[v][64..128) = sum y[src] - dO*y[v]  (O half),
// A[v][128..192) likewise (I half). Reads/writes disjoint lines of A.
__global__ __launch_bounds__(256) void gather_sum(f16* __restrict__ A,
                                                  const int* __restrict__ deg,
                                                  const int* __restrict__ off,
                                                  const int* __restrict__ srcList,
                                                  int N) {
    int wid = (blockIdx.x * 256 + threadIdx.x) >> 6;
    int lane = threadIdx.x & 63;
    if (wid >= 2 * N) return;
    int d = deg[wid];
    int end = off[wid];
    int start = end - d;
    int v = (wid < N) ? wid : wid - N;

    float s0 = 0.f, s1 = 0.f, s2 = 0.f, s3 = 0.f;
    int e = start;
    for (; e + 4 <= end; e += 4) {
        int i0 = srcList[e], i1 = srcList[e + 1];
        int i2 = srcList[e + 2], i3 = srcList[e + 3];
        s0 += (float)A[(size_t)i0 * 192 + lane];
        s1 += (float)A[(size_t)i1 * 192 + lane];
        s2 += (float)A[(size_t)i2 * 192 + lane];
        s3 += (float)A[(size_t)i3 * 192 + lane];
    }
    for (; e < end; e++) s0 += (float)A[(size_t)srcList[e] * 192 + lane];
    float sum = (s0 + s1) + (s2 + s3);
    float yv = (float)A[(size_t)v * 192 + lane];
    float a = sum - (float)d * yv;
    A[(size_t)v * 192 + (wid < N ? 64 : 128) + lane] = (f16)a;
}

// C[N,64] = A[N,192] @ B[192,64] via mfma_f32_16x16x32_f16, A-frags straight
// from global (rows contiguous), B-frags from f16 Wf (L1-broadcast). No LDS.
__global__ __launch_bounds__(256) void gemv_mfma(const f16* __restrict__ A,
                                                 const f16* __restrict__ Wf,
                                                 const int* __restrict__ deg,
                                                 const float* __restrict__ b_O,
                                                 const float* __restrict__ b_I,
                                                 const float* __restrict__ b_S,
                                                 float* __restrict__ out,
                                                 int N, int nTiles) {
    int gw = (blockIdx.x * 256 + threadIdx.x) >> 6;
    int nw = gridDim.x * 4;
    const int lane = threadIdx.x & 63;
    const int mlane = lane & 15;
    const int koff = (lane >> 4) * 8;

    for (int tile = gw; tile < nTiles; tile += nw) {
        const int vbase = tile * 16;
        int va = vbase + mlane; if (va >= N) va = N - 1;
        const f16* arow = A + (size_t)va * 192 + koff;
        f16x8 af[6];
        #pragma unroll
        for (int s = 0; s < 6; s++) af[s] = *(const f16x8*)(arow + s * 32);

        f32x4 accs[4];
        #pragma unroll
        for (int c = 0; c < 4; c++) {
            f32x4 acc = {0.f, 0.f, 0.f, 0.f};
            #pragma unroll
            for (int s = 0; s < 6; s++) {
                int k = s * 32 + koff;
                const f16* bp = Wf + (k >> 6) * 4096 + (c * 16 + mlane) * 64 + (k & 63);
                f16x8 bf = *(const f16x8*)bp;
                acc = __builtin_amdgcn_mfma_f32_16x16x32_f16(af[s], bf, acc, 0, 0, 0);
            }
            accs[c] = acc;
        }

        // C/D layout: col = lane&15, row = (lane>>4)*4 + reg
        const int mrow0 = (lane >> 4) * 4;
        #pragma unroll
        for (int reg = 0; reg < 4; reg++) {
            int v = vbase + mrow0 + reg;
            if (v >= N) continue;
            float cO = (float)deg[v], cI = (float)deg[N + v];
            #pragma unroll
            for (int c = 0; c < 4; c++) {
                int j = c * 16 + mlane;
                out[(size_t)v * DF + j] = accs[c][reg] + b_S[j] + cO * b_O[j] + cI * b_I[j];
            }
        }
    }
}

__global__ void r_transform(const float* __restrict__ r,
                            const float* __restrict__ W_R,
                            const float* __restrict__ b_R,
                            float* __restrict__ out, int N) {
    int j = threadIdx.x;  // 64 threads
    float s = b_R[j];
    #pragma unroll 16
    for (int k = 0; k < 64; k++) s += r[k] * W_R[j * 64 + k];
    out[(size_t)N * DF + j] = s;
}

extern "C" void kernel_launch(void* const* d_in, const int* in_sizes, int n_in,
                              void* d_out, int out_size, void* d_ws, size_t ws_size,
                              hipStream_t stream) {
    const float* x   = (const float*)d_in[0];
    const float* r   = (const float*)d_in[1];
    const int*   src = (const int*)d_in[2];
    const int*   dst = (const int*)d_in[3];
    const float* W_O = (const float*)d_in[4];
    const float* b_O = (const float*)d_in[5];
    const float* W_I = (const float*)d_in[6];
    const float* b_I = (const float*)d_in[7];
    const float* W_S = (const float*)d_in[8];
    const float* b_S = (const float*)d_in[9];
    const float* W_R = (const float*)d_in[10];
    const float* b_R = (const float*)d_in[11];
    float* out = (float*)d_out;

    const int N = in_sizes[0] / DF;
    const int E = in_sizes[2];
    const int half = E / 2;
    const int M = 2 * N;
    const int NB = (M + 255) >> BSH;

    // ws: A[N*192] f16 | Wf[3*4096] f16 | deg[2N] | off[2N] | srcList[E]
    //     | bucketCnt[NB*CPAD] | cur[NB*CPAD] | bucketBase[NB] | pairBuf[E]
    f16* A  = (f16*)d_ws;
    f16* Wf = A + (size_t)N * 192;
    int* deg        = (int*)(Wf + 3 * 4096);
    int* off        = deg + M;
    int* srcList    = off + M;
    int* bucketCnt  = srcList + E;
    int* cur        = bucketCnt + NB * CPAD;
    int* bucketBase = cur + NB * CPAD;
    unsigned int* pairBuf = (unsigned int*)(bucketBase + NB);

    hipMemsetAsync(bucketCnt, 0, (size_t)NB * CPAD * sizeof(int), stream);

    int prepGrid = (N * 32 + 255) / 256;
    prep<<<prepGrid, 256, 0, stream>>>(x, r, A, W_S, W_O, W_I, Wf, N);
    bucket_count<<<256, 256, 0, stream>>>(dst, bucketCnt, E, half, N, NB);
    bucket_scan<<<1, 1024, 0, stream>>>(bucketCnt, bucketBase, cur, NB);
    scatter_pairs<<<(E + 255) / 256, 256, 0, stream>>>(src, dst, cur, pairBuf,
                                                       E, half, N);
    bucket_sort<<<NB, 256, 0, stream>>>(pairBuf, bucketBase, bucketCnt,
                                        deg, off, srcList, M);

    int gsBlocks = (2 * N + 3) / 4;        // one wave per (node, half)
    gather_sum<<<gsBlocks, 256, 0, stream>>>(A, deg, off, srcList, N);

    int nTiles = (N + 15) / 16;
    gemv_mfma<<<1024, 256, 0, stream>>>(A, Wf, deg, b_O, b_I, b_S, out, N, nTiles);
    r_transform<<<1, 64, 0, stream>>>(r, W_R, b_R, out, N);
}

// Round 6
// 248.339 us; speedup vs baseline: 2.3283x; 1.2053x over previous
//
#include <hip/hip_runtime.h>

// CompGraphConv round 6: slotted buckets + fused O/I windows.
//
// Pipeline: prep (y=x-r -> A rows, W->f16, AND pair scatter into fixed-CAP
// bucket slots) -> bucket_sort (LDS counting sort per bucket, writes sorted
// src in-place into pairBuf + dense deg/off) -> gather_sum (ONE wave per
// node handles adjacent O+I windows, batched 8/4/1 gathers) -> gemv_mfma
// (MFMA from global, no LDS) -> r_transform.
//
// Key = (dst<<1)|isI  =>  a node's O and I windows are adjacent in the
// sorted order (same bucket always, since keys 2v,2v+1 share key>>8).
// Round-5's bucket_count+bucket_scan launches are deleted: fixed 2048-slot
// buckets (Poisson mean 1536, sigma 39 -> 13-sigma headroom) need no scan.

#define DF 64
#define CAP 2048            // slots per bucket (mean 1536, 13-sigma safe)
#define CPAD 16             // ints per bucket cursor (64B line)
typedef _Float16 f16;
typedef f16 f16x8 __attribute__((ext_vector_type(8)));
typedef f16 f16x2 __attribute__((ext_vector_type(2)));
typedef float f32x4 __attribute__((ext_vector_type(4)));

// y = x - r into A rows; W_{S,O,I} -> f16 Wf; edge pair scatter.
__global__ __launch_bounds__(256) void prep(const float* __restrict__ x,
                                            const float* __restrict__ r,
                                            f16* __restrict__ A,
                                            const float* __restrict__ W_S,
                                            const float* __restrict__ W_O,
                                            const float* __restrict__ W_I,
                                            f16* __restrict__ Wf,
                                            const int* __restrict__ src,
                                            const int* __restrict__ dst,
                                            int* __restrict__ cur,
                                            unsigned int* __restrict__ pairBuf,
                                            int N, int E, int half) {
    int t = blockIdx.x * 256 + threadIdx.x;
    int ny = N * 32;                      // f16x2 pairs of y
    if (t < ny) {
        int v = t >> 5, k = (t & 31) * 2;
        float y0 = x[(size_t)v * DF + k]     - r[k];
        float y1 = x[(size_t)v * DF + k + 1] - r[k + 1];
        f16x2 p = {(f16)y0, (f16)y1};
        *(f16x2*)(A + (size_t)v * 192 + k) = p;
    }
    if (t < 6144) {                       // 3*4096 weight elems as pairs
        int w = t / 2048;
        int i = (t % 2048) * 2;
        const float* W = (w == 0) ? W_S : (w == 1) ? W_O : W_I;
        f16x2 p = {(f16)W[i], (f16)W[i + 1]};
        *(f16x2*)(Wf + w * 4096 + i) = p;
    }
    if (t < E) {
        int key = (dst[t] << 1) | (t >= half ? 1 : 0);
        int b = key >> 8;
        int pos = atomicAdd(&cur[b * CPAD], 1);
        if (pos < CAP)
            pairBuf[(size_t)b * CAP + pos] =
                (unsigned int)src[t] | ((unsigned int)(key & 255) << 24);
    }
}

// Per-bucket LDS counting sort; sorted src written IN PLACE into pairBuf.
__global__ __launch_bounds__(256) void bucket_sort(unsigned int* __restrict__ pairBuf,
                                                   const int* __restrict__ cur,
                                                   int* __restrict__ deg,
                                                   int* __restrict__ off, int M) {
    __shared__ unsigned int P[CAP];
    __shared__ int cnt[256];
    __shared__ int pos[256];
    int b = blockIdx.x;
    int base = b * CAP;
    int n = cur[b * CPAD];
    if (n > CAP) n = CAP;
    int t = threadIdx.x;
    cnt[t] = 0;
    __syncthreads();
    for (int i = t; i < n; i += 256) {
        unsigned int p = pairBuf[base + i];
        P[i] = p;
        atomicAdd(&cnt[p >> 24], 1);
    }
    __syncthreads();
    int v = cnt[t];
    pos[t] = v;
    __syncthreads();
    #pragma unroll
    for (int o = 1; o < 256; o <<= 1) {
        int u = (t >= o) ? pos[t - o] : 0;
        __syncthreads();
        pos[t] += u;
        __syncthreads();
    }
    int incl = pos[t];
    int key = (b << 8) + t;
    if (key < M) {
        deg[key] = v;
        off[key] = base + incl;          // absolute end; start = end - deg
    }
    __syncthreads();
    pos[t] = incl - v;                   // per-key exclusive cursor
    __syncthreads();
    for (int i = t; i < n; i += 256) {
        unsigned int p = P[i];
        int lk = p >> 24;
        int loc = atomicAdd(&pos[lk], 1);
        pairBuf[base + loc] = p & 0xFFFFFFu;   // in-place sorted src
    }
}

// One wave per NODE: O window [endO-dO, endO) and I window [endO, endI) are
// adjacent. Batched 8/4/1 gathers over the combined window for MLP.
__global__ __launch_bounds__(256) void gather_sum(f16* __restrict__ A,
                                                  const int* __restrict__ deg,
                                                  const int* __restrict__ off,
                                                  const unsigned int* __restrict__ srcList,
                                                  int N) {
    int v = (blockIdx.x * 256 + threadIdx.x) >> 6;
    int lane = threadIdx.x & 63;
    if (v >= N) return;
    int dO = deg[2 * v], dI = deg[2 * v + 1];
    int endO = off[2 * v], endI = off[2 * v + 1];
    int start = endO - dO;

    float sO = 0.f, sI = 0.f;
    int e = start;
    for (; e + 8 <= endI; e += 8) {
        float val[8];
        #pragma unroll
        for (int j = 0; j < 8; j++) {
            unsigned int s = srcList[e + j];
            val[j] = (float)A[(size_t)s * 192 + lane];
        }
        #pragma unroll
        for (int j = 0; j < 8; j++) {
            if (e + j < endO) sO += val[j]; else sI += val[j];
        }
    }
    if (e + 4 <= endI) {
        float val[4];
        #pragma unroll
        for (int j = 0; j < 4; j++) {
            unsigned int s = srcList[e + j];
            val[j] = (float)A[(size_t)s * 192 + lane];
        }
        #pragma unroll
        for (int j = 0; j < 4; j++) {
            if (e + j < endO) sO += val[j]; else sI += val[j];
        }
        e += 4;
    }
    for (; e < endI; e++) {
        float vv = (float)A[(size_t)srcList[e] * 192 + lane];
        if (e < endO) sO += vv; else sI += vv;
    }

    float yv = (float)A[(size_t)v * 192 + lane];
    A[(size_t)v * 192 + 64 + lane]  = (f16)(sO - (float)dO * yv);
    A[(size_t)v * 192 + 128 + lane] = (f16)(sI - (float)dI * yv);
}

// C[N,64] = A[N,192] @ B[192,64] via mfma_f32_16x16x32_f16, A-frags straight
// from global (rows contiguous), B-frags from f16 Wf (L1-broadcast). No LDS.
__global__ __launch_bounds__(256) void gemv_mfma(const f16* __restrict__ A,
                                                 const f16* __restrict__ Wf,
                                                 const int* __restrict__ deg,
                                                 const float* __restrict__ b_O,
                                                 const float* __restrict__ b_I,
                                                 const float* __restrict__ b_S,
                                                 float* __restrict__ out,
                                                 int N, int nTiles) {
    int gw = (blockIdx.x * 256 + threadIdx.x) >> 6;
    int nw = gridDim.x * 4;
    const int lane = threadIdx.x & 63;
    const int mlane = lane & 15;
    const int koff = (lane >> 4) * 8;

    for (int tile = gw; tile < nTiles; tile += nw) {
        const int vbase = tile * 16;
        int va = vbase + mlane; if (va >= N) va = N - 1;
        const f16* arow = A + (size_t)va * 192 + koff;
        f16x8 af[6];
        #pragma unroll
        for (int s = 0; s < 6; s++) af[s] = *(const f16x8*)(arow + s * 32);

        f32x4 accs[4];
        #pragma unroll
        for (int c = 0; c < 4; c++) {
            f32x4 acc = {0.f, 0.f, 0.f, 0.f};
            #pragma unroll
            for (int s = 0; s < 6; s++) {
                int k = s * 32 + koff;
                const f16* bp = Wf + (k >> 6) * 4096 + (c * 16 + mlane) * 64 + (k & 63);
                f16x8 bf = *(const f16x8*)bp;
                acc = __builtin_amdgcn_mfma_f32_16x16x32_f16(af[s], bf, acc, 0, 0, 0);
            }
            accs[c] = acc;
        }

        // C/D layout: col = lane&15, row = (lane>>4)*4 + reg
        const int mrow0 = (lane >> 4) * 4;
        #pragma unroll
        for (int reg = 0; reg < 4; reg++) {
            int v = vbase + mrow0 + reg;
            if (v >= N) continue;
            float cO = (float)deg[2 * v], cI = (float)deg[2 * v + 1];
            #pragma unroll
            for (int c = 0; c < 4; c++) {
                int j = c * 16 + mlane;
                out[(size_t)v * DF + j] = accs[c][reg] + b_S[j] + cO * b_O[j] + cI * b_I[j];
            }
        }
    }
}

__global__ void r_transform(const float* __restrict__ r,
                            const float* __restrict__ W_R,
                            const float* __restrict__ b_R,
                            float* __restrict__ out, int N) {
    int j = threadIdx.x;  // 64 threads
    float s = b_R[j];
    #pragma unroll 16
    for (int k = 0; k < 64; k++) s += r[k] * W_R[j * 64 + k];
    out[(size_t)N * DF + j] = s;
}

extern "C" void kernel_launch(void* const* d_in, const int* in_sizes, int n_in,
                              void* d_out, int out_size, void* d_ws, size_t ws_size,
                              hipStream_t stream) {
    const float* x   = (const float*)d_in[0];
    const float* r   = (const float*)d_in[1];
    const int*   src = (const int*)d_in[2];
    const int*   dst = (const int*)d_in[3];
    const float* W_O = (const float*)d_in[4];
    const float* b_O = (const float*)d_in[5];
    const float* W_I = (const float*)d_in[6];
    const float* b_I = (const float*)d_in[7];
    const float* W_S = (const float*)d_in[8];
    const float* b_S = (const float*)d_in[9];
    const float* W_R = (const float*)d_in[10];
    const float* b_R = (const float*)d_in[11];
    float* out = (float*)d_out;

    const int N = in_sizes[0] / DF;
    const int E = in_sizes[2];
    const int half = E / 2;
    const int M = 2 * N;                 // keys: (dst<<1)|isI
    const int NB = (M + 255) >> 8;       // 256 keys per bucket

    // ws: A[N*192] f16 | Wf[3*4096] f16 | deg[2N] | off[2N]
    //     | cur[NB*CPAD] | pairBuf[NB*CAP]          (~46 MB)
    f16* A  = (f16*)d_ws;
    f16* Wf = A + (size_t)N * 192;
    int* deg = (int*)(Wf + 3 * 4096);
    int* off = deg + M;
    int* cur = off + M;
    unsigned int* pairBuf = (unsigned int*)(cur + (size_t)NB * CPAD);

    hipMemsetAsync(cur, 0, (size_t)NB * CPAD * sizeof(int), stream);

    int nThread = N * 32;                // dominates E and 6144
    prep<<<(nThread + 255) / 256, 256, 0, stream>>>(x, r, A, W_S, W_O, W_I, Wf,
                                                    src, dst, cur, pairBuf,
                                                    N, E, half);
    bucket_sort<<<NB, 256, 0, stream>>>(pairBuf, cur, deg, off, M);

    int gsBlocks = (N + 3) / 4;          // one wave per node (O+I fused)
    gather_sum<<<gsBlocks, 256, 0, stream>>>(A, deg, off, pairBuf, N);

    int nTiles = (N + 15) / 16;
    gemv_mfma<<<1024, 256, 0, stream>>>(A, Wf, deg, b_O, b_I, b_S, out, N, nTiles);
    r_transform<<<1, 64, 0, stream>>>(r, W_R, b_R, out, N);
}

// Round 7
// 233.826 us; speedup vs baseline: 2.4728x; 1.0621x over previous
//
#include <hip/hip_runtime.h>

// CompGraphConv round 7: XCD-local bucket slots + pair-of-nodes gather.
//
// Round-6 prep wrote 73.6 MB for ~17.6 MB payload: pair-scatter slot lines
// were dirtied by all 8 XCDs (non-coherent L2s -> one 64B line written back
// up to 16x). Fix: sub-slot each bucket by g = blockIdx.x & 7 (round-robin
// block->XCD heuristic; wrong mapping = no harm). Each (bucket,g) region is
// appended by ONE XCD -> active line stays hot in its L2 until full.
// bucket_sort concatenates the 8 segments in LDS, sorts, writes back IN
// PLACE at the bucket base (block-local region, reads precede writes).
//
// gather_sum: one wave per node PAIR. Keys 4p..4p+3 never straddle a
// bucket boundary (boundaries at multiples of 256, 4p = 0 mod 4), so the
// 4 windows are one contiguous range; batched-16 gathers + 3-threshold
// prefix accumulators double MLP and halve wave count.

#define DF 64
#define SEGS 8              // XCD sub-slots per bucket
#define SCAP 320            // entries per (bucket,g): mean 192, ~9 sigma
#define BCAP (SEGS * SCAP)  // 2560 slots per bucket region
#define CPAD 16             // ints per cursor (one 64B line each)
typedef _Float16 f16;
typedef f16 f16x8 __attribute__((ext_vector_type(8)));
typedef f16 f16x2 __attribute__((ext_vector_type(2)));
typedef float f32x4 __attribute__((ext_vector_type(4)));

// y = x - r into A rows; W_{S,O,I} -> f16 Wf; XCD-local edge pair scatter.
__global__ __launch_bounds__(256) void prep(const float* __restrict__ x,
                                            const float* __restrict__ r,
                                            f16* __restrict__ A,
                                            const float* __restrict__ W_S,
                                            const float* __restrict__ W_O,
                                            const float* __restrict__ W_I,
                                            f16* __restrict__ Wf,
                                            const int* __restrict__ src,
                                            const int* __restrict__ dst,
                                            int* __restrict__ cur,
                                            unsigned int* __restrict__ pairBuf,
                                            int N, int E, int half) {
    int t = blockIdx.x * 256 + threadIdx.x;
    int ny = N * 32;                      // f16x2 pairs of y
    if (t < ny) {
        int v = t >> 5, k = (t & 31) * 2;
        float y0 = x[(size_t)v * DF + k]     - r[k];
        float y1 = x[(size_t)v * DF + k + 1] - r[k + 1];
        f16x2 p = {(f16)y0, (f16)y1};
        *(f16x2*)(A + (size_t)v * 192 + k) = p;
    }
    if (t < 6144) {                       // 3*4096 weight elems as pairs
        int w = t / 2048;
        int i = (t % 2048) * 2;
        const float* W = (w == 0) ? W_S : (w == 1) ? W_O : W_I;
        f16x2 p = {(f16)W[i], (f16)W[i + 1]};
        *(f16x2*)(Wf + w * 4096 + i) = p;
    }
    if (t < E) {
        int key = (dst[t] << 1) | (t >= half ? 1 : 0);
        int b = key >> 8;
        int c = b * SEGS + (blockIdx.x & (SEGS - 1));   // XCD-local sub-slot
        int pos = atomicAdd(&cur[c * CPAD], 1);
        if (pos < SCAP)
            pairBuf[(size_t)c * SCAP + pos] =
                (unsigned int)src[t] | ((unsigned int)(key & 255) << 24);
    }
}

// Per-bucket LDS counting sort over the 8 concatenated segments; sorted src
// written in place at the bucket's own region base.
__global__ __launch_bounds__(256) void bucket_sort(unsigned int* __restrict__ pairBuf,
                                                   const int* __restrict__ cur,
                                                   int* __restrict__ deg,
                                                   int* __restrict__ off, int M) {
    __shared__ unsigned int P[2048];
    __shared__ int cnt[256];
    __shared__ int pos[256];
    int b = blockIdx.x;
    int t = threadIdx.x;
    cnt[t] = 0;
    __syncthreads();
    int o = 0;
    #pragma unroll
    for (int g = 0; g < SEGS; g++) {
        int n = cur[(b * SEGS + g) * CPAD];
        if (n > SCAP) n = SCAP;
        const unsigned int* seg = pairBuf + (size_t)(b * SEGS + g) * SCAP;
        for (int i = t; i < n; i += 256) {
            int idx = o + i;
            if (idx < 2048) {
                unsigned int p = seg[i];
                P[idx] = p;
                atomicAdd(&cnt[p >> 24], 1);
            }
        }
        o += n;
    }
    int total = (o > 2048) ? 2048 : o;
    __syncthreads();
    int v = cnt[t];
    pos[t] = v;
    __syncthreads();
    #pragma unroll
    for (int s = 1; s < 256; s <<= 1) {
        int u = (t >= s) ? pos[t - s] : 0;
        __syncthreads();
        pos[t] += u;
        __syncthreads();
    }
    int incl = pos[t];
    int key = (b << 8) + t;
    if (key < M) {
        deg[key] = v;
        off[key] = b * BCAP + incl;      // absolute end; start = end - deg
    }
    __syncthreads();
    pos[t] = incl - v;                   // per-key exclusive cursor
    __syncthreads();
    unsigned int* outb = pairBuf + (size_t)b * BCAP;
    for (int i = t; i < total; i += 256) {
        unsigned int p = P[i];
        int lk = p >> 24;
        int loc = atomicAdd(&pos[lk], 1);
        outb[loc] = p & 0xFFFFFFu;       // dense sorted src, in place
    }
}

// One wave per node pair (2p, 2p+1): keys 4p..4p+3 form ONE contiguous
// range [s, end) with thresholds t1,t2,t3. Batched 16/4/1 gathers; prefix
// accumulators sAll, s>=t1, s>=t2, s>=t3 recover the four window sums.
__global__ __launch_bounds__(256) void gather_sum(f16* __restrict__ A,
                                                  const int* __restrict__ deg,
                                                  const int* __restrict__ off,
                                                  const unsigned int* __restrict__ srcList,
                                                  int N) {
    int p = (blockIdx.x * 256 + threadIdx.x) >> 6;
    int lane = threadIdx.x & 63;
    int v0 = 2 * p, v1 = 2 * p + 1;
    if (v0 >= N) return;
    bool hasV1 = (v1 < N);
    int dO0 = deg[4 * p], dI0 = deg[4 * p + 1];
    int dO1 = hasV1 ? deg[4 * p + 2] : 0;
    int dI1 = hasV1 ? deg[4 * p + 3] : 0;
    int s = off[4 * p] - dO0;
    int t1 = s + dO0, t2 = t1 + dI0, t3 = t2 + dO1;
    int end = t3 + dI1;

    float sAll = 0.f, sG1 = 0.f, sG2 = 0.f, sG3 = 0.f;
    int e = s;
    for (; e + 16 <= end; e += 16) {
        float val[16];
        #pragma unroll
        for (int j = 0; j < 16; j++)
            val[j] = (float)A[(size_t)srcList[e + j] * 192 + lane];
        #pragma unroll
        for (int j = 0; j < 16; j++) {
            int q = e + j;
            sAll += val[j];
            sG1 += (q >= t1) ? val[j] : 0.f;
            sG2 += (q >= t2) ? val[j] : 0.f;
            sG3 += (q >= t3) ? val[j] : 0.f;
        }
    }
    for (; e + 4 <= end; e += 4) {
        float val[4];
        #pragma unroll
        for (int j = 0; j < 4; j++)
            val[j] = (float)A[(size_t)srcList[e + j] * 192 + lane];
        #pragma unroll
        for (int j = 0; j < 4; j++) {
            int q = e + j;
            sAll += val[j];
            sG1 += (q >= t1) ? val[j] : 0.f;
            sG2 += (q >= t2) ? val[j] : 0.f;
            sG3 += (q >= t3) ? val[j] : 0.f;
        }
    }
    for (; e < end; e++) {
        float vv = (float)A[(size_t)srcList[e] * 192 + lane];
        sAll += vv;
        sG1 += (e >= t1) ? vv : 0.f;
        sG2 += (e >= t2) ? vv : 0.f;
        sG3 += (e >= t3) ? vv : 0.f;
    }

    float sO0 = sAll - sG1, sI0 = sG1 - sG2, sO1 = sG2 - sG3, sI1 = sG3;
    float y0 = (float)A[(size_t)v0 * 192 + lane];
    A[(size_t)v0 * 192 + 64 + lane]  = (f16)(sO0 - (float)dO0 * y0);
    A[(size_t)v0 * 192 + 128 + lane] = (f16)(sI0 - (float)dI0 * y0);
    if (hasV1) {
        float y1 = (float)A[(size_t)v1 * 192 + lane];
        A[(size_t)v1 * 192 + 64 + lane]  = (f16)(sO1 - (float)dO1 * y1);
        A[(size_t)v1 * 192 + 128 + lane] = (f16)(sI1 - (float)dI1 * y1);
    }
}

// C[N,64] = A[N,192] @ B[192,64] via mfma_f32_16x16x32_f16, A-frags straight
// from global (rows contiguous), B-frags from f16 Wf (L1-broadcast). No LDS.
__global__ __launch_bounds__(256) void gemv_mfma(const f16* __restrict__ A,
                                                 const f16* __restrict__ Wf,
                                                 const int* __restrict__ deg,
                                                 const float* __restrict__ b_O,
                                                 const float* __restrict__ b_I,
                                                 const float* __restrict__ b_S,
                                                 float* __restrict__ out,
                                                 int N, int nTiles) {
    int gw = (blockIdx.x * 256 + threadIdx.x) >> 6;
    int nw = gridDim.x * 4;
    const int lane = threadIdx.x & 63;
    const int mlane = lane & 15;
    const int koff = (lane >> 4) * 8;

    for (int tile = gw; tile < nTiles; tile += nw) {
        const int vbase = tile * 16;
        int va = vbase + mlane; if (va >= N) va = N - 1;
        const f16* arow = A + (size_t)va * 192 + koff;
        f16x8 af[6];
        #pragma unroll
        for (int s = 0; s < 6; s++) af[s] = *(const f16x8*)(arow + s * 32);

        f32x4 accs[4];
        #pragma unroll
        for (int c = 0; c < 4; c++) {
            f32x4 acc = {0.f, 0.f, 0.f, 0.f};
            #pragma unroll
            for (int s = 0; s < 6; s++) {
                int k = s * 32 + koff;
                const f16* bp = Wf + (k >> 6) * 4096 + (c * 16 + mlane) * 64 + (k & 63);
                f16x8 bf = *(const f16x8*)bp;
                acc = __builtin_amdgcn_mfma_f32_16x16x32_f16(af[s], bf, acc, 0, 0, 0);
            }
            accs[c] = acc;
        }

        // C/D layout: col = lane&15, row = (lane>>4)*4 + reg
        const int mrow0 = (lane >> 4) * 4;
        #pragma unroll
        for (int reg = 0; reg < 4; reg++) {
            int v = vbase + mrow0 + reg;
            if (v >= N) continue;
            float cO = (float)deg[2 * v], cI = (float)deg[2 * v + 1];
            #pragma unroll
            for (int c = 0; c < 4; c++) {
                int j = c * 16 + mlane;
                out[(size_t)v * DF + j] = accs[c][reg] + b_S[j] + cO * b_O[j] + cI * b_I[j];
            }
        }
    }
}

__global__ void r_transform(const float* __restrict__ r,
                            const float* __restrict__ W_R,
                            const float* __restrict__ b_R,
                            float* __restrict__ out, int N) {
    int j = threadIdx.x;  // 64 threads
    float s = b_R[j];
    #pragma unroll 16
    for (int k = 0; k < 64; k++) s += r[k] * W_R[j * 64 + k];
    out[(size_t)N * DF + j] = s;
}

extern "C" void kernel_launch(void* const* d_in, const int* in_sizes, int n_in,
                              void* d_out, int out_size, void* d_ws, size_t ws_size,
                              hipStream_t stream) {
    const float* x   = (const float*)d_in[0];
    const float* r   = (const float*)d_in[1];
    const int*   src = (const int*)d_in[2];
    const int*   dst = (const int*)d_in[3];
    const float* W_O = (const float*)d_in[4];
    const float* b_O = (const float*)d_in[5];
    const float* W_I = (const float*)d_in[6];
    const float* b_I = (const float*)d_in[7];
    const float* W_S = (const float*)d_in[8];
    const float* b_S = (const float*)d_in[9];
    const float* W_R = (const float*)d_in[10];
    const float* b_R = (const float*)d_in[11];
    float* out = (float*)d_out;

    const int N = in_sizes[0] / DF;
    const int E = in_sizes[2];
    const int half = E / 2;
    const int M = 2 * N;                 // keys: (dst<<1)|isI
    const int NB = (M + 255) >> 8;       // 256 keys per bucket

    // ws: A[N*192] f16 | Wf[3*4096] f16 | deg[2N] | off[2N]
    //     | cur[NB*SEGS*CPAD] | pairBuf[NB*BCAP]      (~48 MB)
    f16* A  = (f16*)d_ws;
    f16* Wf = A + (size_t)N * 192;
    int* deg = (int*)(Wf + 3 * 4096);
    int* off = deg + M;
    int* cur = off + M;
    unsigned int* pairBuf = (unsigned int*)(cur + (size_t)NB * SEGS * CPAD);

    hipMemsetAsync(cur, 0, (size_t)NB * SEGS * CPAD * sizeof(int), stream);

    int nThread = N * 32;                // dominates E and 6144
    prep<<<(nThread + 255) / 256, 256, 0, stream>>>(x, r, A, W_S, W_O, W_I, Wf,
                                                    src, dst, cur, pairBuf,
                                                    N, E, half);
    bucket_sort<<<NB, 256, 0, stream>>>(pairBuf, cur, deg, off, M);

    int nPairs = (N + 1) / 2;            // one wave per node pair
    int gsBlocks = (nPairs + 3) / 4;
    gather_sum<<<gsBlocks, 256, 0, stream>>>(A, deg, off, pairBuf, N);

    int nTiles = (N + 15) / 16;
    gemv_mfma<<<1024, 256, 0, stream>>>(A, Wf, deg, b_O, b_I, b_S, out, N, nTiles);
    r_transform<<<1, 64, 0, stream>>>(r, W_R, b_R, out, N);
}